// Round 11
// baseline (106.582 us; speedup 1.0000x reference)
//
#include <hip/hip_runtime.h>
#include <hip/hip_bf16.h>
#include <math.h>

#define N 8192
#define D 256
#define MARGIN 0.3f
#define EPS 1e-12f

#define BT 128                             // block tile (i and j)
#define NJB (N / BT)                       // 64 tile-blocks per dim
#define TOTAL_TRI (NJB * (NJB + 1) / 2)    // 2080 upper-triangle tiles = 8 * 260

typedef __attribute__((ext_vector_type(8))) short short8;   // 8 bf16 in 4 VGPRs
typedef __attribute__((ext_vector_type(4))) float floatx4;  // MFMA C/D

static __device__ inline ushort f2bf(float f) {
    __hip_bfloat16 h = __float2bfloat16(f);
    return *reinterpret_cast<ushort*>(&h);
}

// fn16t layout (MFMA-fragment-tiled): element (row r, k) lives at
//   chunk c = (r>>4)*8 + (k>>5), offset (((k>>3)&3)*16 + (r&15))*8 + (k&7)
// so a wave (lane = quad*16+l15) loads fragment (rows g*16..+15, k-step kk) as ONE contiguous
// 1KB transaction: *(short8*)(fn16t + c*512 + lane*8).

// ---------------- Kernel 1: L2 normalize -> bf16 in tiled layout (16 rows/block) -------------
__global__ __launch_bounds__(256) void normalize_kernel(const float* __restrict__ x,
                                                        ushort* __restrict__ fn16t,
                                                        float* __restrict__ out) {
    __shared__ ushort lnorm[16][256];     // 8 KB
    const int g    = blockIdx.x;          // group of 16 rows
    const int t    = threadIdx.x;
    const int w    = t >> 6;
    const int lane = t & 63;
    if (g == 0 && t == 0) out[0] = 0.0f;

    #pragma unroll
    for (int rr = 0; rr < 4; rr++) {
        const int rl  = w * 4 + rr;       // local row 0..15
        const int row = g * 16 + rl;
        float4 v = ((const float4*)(x + (size_t)row * D))[lane];
        float s = v.x * v.x + v.y * v.y + v.z * v.z + v.w * v.w;
        #pragma unroll
        for (int off = 32; off; off >>= 1) s += __shfl_down(s, off);
        s = __shfl(s, 0);
        const float inv = 1.0f / fmaxf(sqrtf(s), 1e-12f);
        ushort4 b;
        b.x = f2bf(v.x * inv); b.y = f2bf(v.y * inv);
        b.z = f2bf(v.z * inv); b.w = f2bf(v.w * inv);
        *(ushort4*)(&lnorm[rl][lane * 4]) = b;
    }
    __syncthreads();
    // write tiled: thread t covers chunk kk = t>>5, two lane-slots p = (t&31)*2 + {0,1}
    const int kk = t >> 5;
    const int pp = (t & 31) * 2;
    ushort* base = fn16t + ((size_t)g * 8 + kk) * 512;
    #pragma unroll
    for (int e = 0; e < 2; e++) {
        const int p    = pp + e;
        const int quad = p >> 4;
        const int l15  = p & 15;
        *(short8*)(base + p * 8) = *(const short8*)(&lnorm[l15][kk * 32 + quad * 8]);
    }
}

// ---------------- Kernel 2: triangular MFMA gram, pipelined barrier-free K-loop --------------
// Upper-triangle tiles (jb >= ib), XCD-swizzled (2080 = 8*260: blockIdx%8 selects XCD-local
// contiguous tile range -> A-tiles stay hot in that XCD's private L2). No LDS staging: waves
// stream contiguous 1KB fragment loads from the tiled fn16t. Depth-2 explicit double-buffer:
// MFMA consumes buffer kk&1 while loads for kk+2 are in flight (breaks the R10 serial
// load->waitcnt(0)->MFMA pattern caused by the 80-VGPR allocation). launch_bounds(256,2)
// deliberately trades occupancy for prefetch registers.
// Reductions on g (post-norm ||f||^2==1, d2=2-2g monotone dec: hardest_pos = min g over
// positives, hardest_neg = max g over negatives). Col partials -> slot ib rows j; off-diag row
// partials (16-lane shuffle reduce) -> slot jb rows i. Plain stores, no atomics, no fences.
__global__ __launch_bounds__(256, 2) void gram_kernel(const ushort* __restrict__ fn16t,
                                                      const int* __restrict__ lab,
                                                      float* __restrict__ gp_part,
                                                      float* __restrict__ gn_part) {
    __shared__ float cGp[BT][2], cGn[BT][2];   // j-col partials, per wi half
    __shared__ float rGp[BT][2], rGn[BT][2];   // i-row partials, per wj half

    // XCD swizzle then triangular decode (row-major over jb >= ib)
    const int bidx = blockIdx.x;
    const int idx  = (bidx & 7) * 260 + (bidx >> 3);
    const float c = 2.0f * NJB + 1.0f;
    int ib = (int)((c - sqrtf(c * c - 8.0f * (float)idx)) * 0.5f);
    while (ib > 0 && idx < ib * NJB - ib * (ib - 1) / 2) ib--;
    while (idx >= (ib + 1) * NJB - (ib + 1) * ib / 2) ib++;
    const int jb = ib + (idx - (ib * NJB - ib * (ib - 1) / 2));
    const bool offdiag = (jb > ib);
    const int i0 = ib * BT, j0 = jb * BT;

    const int t    = threadIdx.x;
    const int lane = t & 63;
    const int w    = t >> 6;
    const int wi   = w >> 1, wj = w & 1;        // 2x2 waves, each 64x64
    const int quad = lane >> 4;
    const int l15  = lane & 15;

    // fragment base pointers into the tiled layout (group stride = 4096 ushorts)
    const ushort* pA[4];
    const ushort* pB[4];
    #pragma unroll
    for (int m = 0; m < 4; m++)
        pA[m] = fn16t + ((size_t)(ib * 8 + wi * 4 + m)) * 4096 + lane * 8;
    #pragma unroll
    for (int n = 0; n < 4; n++)
        pB[n] = fn16t + ((size_t)(jb * 8 + wj * 4 + n)) * 4096 + lane * 8;

    floatx4 acc[4][4];
    #pragma unroll
    for (int m = 0; m < 4; m++)
        #pragma unroll
        for (int n = 0; n < 4; n++)
            acc[m][n] = (floatx4){0.f, 0.f, 0.f, 0.f};

    // depth-2 pipelined K-loop: 8 steps of K=32, no barriers
    short8 afb[2][4], bfb[2][4];
    #pragma unroll
    for (int p = 0; p < 2; p++) {
        #pragma unroll
        for (int m = 0; m < 4; m++) afb[p][m] = *(const short8*)(pA[m] + p * 512);
        #pragma unroll
        for (int n = 0; n < 4; n++) bfb[p][n] = *(const short8*)(pB[n] + p * 512);
    }
    #pragma unroll
    for (int kk = 0; kk < 8; kk++) {
        const int cur = kk & 1;
        #pragma unroll
        for (int m = 0; m < 4; m++)
            #pragma unroll
            for (int n = 0; n < 4; n++)
                acc[m][n] = __builtin_amdgcn_mfma_f32_16x16x32_bf16(afb[cur][m], bfb[cur][n], acc[m][n], 0, 0, 0);
        if (kk + 2 < 8) {
            #pragma unroll
            for (int m = 0; m < 4; m++) afb[cur][m] = *(const short8*)(pA[m] + (kk + 2) * 512);
            #pragma unroll
            for (int n = 0; n < 4; n++) bfb[cur][n] = *(const short8*)(pB[n] + (kk + 2) * 512);
        }
    }

    // ---- epilogue on g. C/D layout: col = l15 (tile col wj*64+n*16+l15), row = quad*4 + reg.
    int labj[4];
    #pragma unroll
    for (int n = 0; n < 4; n++) labj[n] = lab[j0 + wj * 64 + n * 16 + l15];
    float gpc[4], gnc[4];
    #pragma unroll
    for (int n = 0; n < 4; n++) { gpc[n] = INFINITY; gnc[n] = -INFINITY; }

    #pragma unroll
    for (int m = 0; m < 4; m++) {
        const int4 li4 = *(const int4*)(lab + i0 + wi * 64 + m * 16 + quad * 4);
        const int labi[4] = {li4.x, li4.y, li4.z, li4.w};
        #pragma unroll
        for (int r = 0; r < 4; r++) {
            float pr = INFINITY, nr = -INFINITY;
            #pragma unroll
            for (int n = 0; n < 4; n++) {
                const float g = acc[m][n][r];
                const bool same = (labi[r] == labj[n]);
                const float selp = same ? g : INFINITY;
                const float seln = same ? -INFINITY : g;
                pr = fminf(pr, selp);           nr = fmaxf(nr, seln);
                gpc[n] = fminf(gpc[n], selp);   gnc[n] = fmaxf(gnc[n], seln);
            }
            if (offdiag) {                      // row-side: 16-lane shuffle reduce
                #pragma unroll
                for (int o = 1; o < 16; o <<= 1) {
                    pr = fminf(pr, __shfl_xor(pr, o));
                    nr = fmaxf(nr, __shfl_xor(nr, o));
                }
                if (l15 == 0) {
                    const int irow = wi * 64 + m * 16 + quad * 4 + r;
                    rGp[irow][wj] = pr; rGn[irow][wj] = nr;
                }
            }
        }
    }
    // column-side: reduce across 4 quads (covers all 64 rows of the wi half)
    #pragma unroll
    for (int n = 0; n < 4; n++) {
        float p = gpc[n], q2 = gnc[n];
        p  = fminf(p,  __shfl_xor(p, 16));  p  = fminf(p,  __shfl_xor(p, 32));
        q2 = fmaxf(q2, __shfl_xor(q2, 16)); q2 = fmaxf(q2, __shfl_xor(q2, 32));
        if (quad == 0) {
            const int col = wj * 64 + n * 16 + l15;
            cGp[col][wi] = p; cGn[col][wi] = q2;
        }
    }
    __syncthreads();
    if (t < BT) {                               // column-side store
        gp_part[(size_t)ib * N + j0 + t] = fminf(cGp[t][0], cGp[t][1]);
        gn_part[(size_t)ib * N + j0 + t] = fmaxf(cGn[t][0], cGn[t][1]);
    } else if (offdiag) {                       // row-side store
        const int i = t - BT;
        gp_part[(size_t)jb * N + i0 + i] = fminf(rGp[i][0], rGp[i][1]);
        gn_part[(size_t)jb * N + i0 + i] = fmaxf(rGn[i][0], rGn[i][1]);
    }
}

// ---------------- Kernel 3: fold slots, sqrt, relu, mean — 256 blocks, coalesced ------------
__global__ __launch_bounds__(256) void reduce_kernel(const float* __restrict__ gp_part,
                                                     const float* __restrict__ gn_part,
                                                     float* __restrict__ out) {
    __shared__ float redp[32][5], redn[32][5];
    const int t  = threadIdx.x;
    const int r  = blockIdx.x * 32 + (t & 31);   // 256 blocks x 32 rows
    const int sg = t >> 5;                        // slot group 0..7
    float gp = INFINITY, gn = -INFINITY;
    #pragma unroll
    for (int q = 0; q < 8; q++) {
        const int s = sg * 8 + q;
        gp = fminf(gp, gp_part[(size_t)s * N + r]);
        gn = fmaxf(gn, gn_part[(size_t)s * N + r]);
    }
    gp = fminf(gp, __shfl_xor(gp, 32));
    gn = fmaxf(gn, __shfl_xor(gn, 32));
    const int w = t >> 6;
    if ((t & 63) < 32) { redp[t & 31][w] = gp; redn[t & 31][w] = gn; }
    __syncthreads();
    if (t < 32) {
        const float p  = fminf(fminf(redp[t][0], redp[t][1]), fminf(redp[t][2], redp[t][3]));
        const float nn = fmaxf(fmaxf(redn[t][0], redn[t][1]), fmaxf(redn[t][2], redn[t][3]));
        const float dp = sqrtf(fmaxf(2.0f - 2.0f * p,  EPS));  // hardest_pos distance
        const float dn = sqrtf(fmaxf(2.0f - 2.0f * nn, EPS));  // hardest_neg distance
        const float l  = dp - dn + MARGIN;
        float sum = (l > 0.0f) ? l : 0.0f;
        #pragma unroll
        for (int off = 16; off; off >>= 1) sum += __shfl_down(sum, off);
        if (t == 0) atomicAdd(out, sum * (1.0f / (float)N));
    }
}

extern "C" void kernel_launch(void* const* d_in, const int* in_sizes, int n_in,
                              void* d_out, int out_size, void* d_ws, size_t ws_size,
                              hipStream_t stream) {
    const float* x   = (const float*)d_in[0];
    const int*   lab = (const int*)d_in[1];
    float* out = (float*)d_out;

    char* ws = (char*)d_ws;
    ushort* fn16t   = (ushort*)ws;                                  // N*D bf16 = 4 MB (tiled)
    float*  gp_part = (float*)(ws + (size_t)N * D * 2);             // NJB*N floats = 2 MB
    float*  gn_part = gp_part + (size_t)NJB * N;                    // NJB*N floats = 2 MB

    normalize_kernel<<<N / 16, 256, 0, stream>>>(x, fn16t, out);
    gram_kernel<<<TOTAL_TRI, 256, 0, stream>>>(fn16t, lab, gp_part, gn_part);
    reduce_kernel<<<N / 32, 256, 0, stream>>>(gp_part, gn_part, out);
}

// Round 12
// 106.195 us; speedup vs baseline: 1.0036x; 1.0036x over previous
//
#include <hip/hip_runtime.h>
#include <hip/hip_bf16.h>
#include <math.h>

#define N 8192
#define D 256
#define MARGIN 0.3f
#define EPS 1e-12f

#define BT 128                             // block tile (i and j)
#define NJB (N / BT)                       // 64 tile-blocks per dim
#define TOTAL_TRI (NJB * (NJB + 1) / 2)    // 2080 upper-triangle tiles = 8 * 260

typedef __attribute__((ext_vector_type(8))) short short8;   // 8 bf16 in 4 VGPRs
typedef __attribute__((ext_vector_type(4))) float floatx4;  // MFMA C/D

static __device__ inline ushort f2bf(float f) {
    __hip_bfloat16 h = __float2bfloat16(f);
    return *reinterpret_cast<ushort*>(&h);
}

// fn16t layout (MFMA-fragment-tiled): element (row r, k) lives at
//   chunk c = (r>>4)*8 + (k>>5), offset (((k>>3)&3)*16 + (r&15))*8 + (k&7)
// so a wave (lane = quad*16+l15) loads fragment (rows g*16..+15, k-step kk) as ONE contiguous
// 1KB transaction: *(short8*)(fn16t + c*512 + lane*8).

// ---------------- Kernel 1: L2 normalize -> bf16 in tiled layout (16 rows/block) -------------
__global__ __launch_bounds__(256) void normalize_kernel(const float* __restrict__ x,
                                                        ushort* __restrict__ fn16t,
                                                        float* __restrict__ out) {
    __shared__ ushort lnorm[16][256];     // 8 KB
    const int g    = blockIdx.x;          // group of 16 rows
    const int t    = threadIdx.x;
    const int w    = t >> 6;
    const int lane = t & 63;
    if (g == 0 && t == 0) out[0] = 0.0f;

    #pragma unroll
    for (int rr = 0; rr < 4; rr++) {
        const int rl  = w * 4 + rr;       // local row 0..15
        const int row = g * 16 + rl;
        float4 v = ((const float4*)(x + (size_t)row * D))[lane];
        float s = v.x * v.x + v.y * v.y + v.z * v.z + v.w * v.w;
        #pragma unroll
        for (int off = 32; off; off >>= 1) s += __shfl_down(s, off);
        s = __shfl(s, 0);
        const float inv = 1.0f / fmaxf(sqrtf(s), 1e-12f);
        ushort4 b;
        b.x = f2bf(v.x * inv); b.y = f2bf(v.y * inv);
        b.z = f2bf(v.z * inv); b.w = f2bf(v.w * inv);
        *(ushort4*)(&lnorm[rl][lane * 4]) = b;
    }
    __syncthreads();
    // write tiled: thread t covers chunk kk = t>>5, two lane-slots p = (t&31)*2 + {0,1}
    const int kk = t >> 5;
    const int pp = (t & 31) * 2;
    ushort* base = fn16t + ((size_t)g * 8 + kk) * 512;
    #pragma unroll
    for (int e = 0; e < 2; e++) {
        const int p    = pp + e;
        const int quad = p >> 4;
        const int l15  = p & 15;
        *(short8*)(base + p * 8) = *(const short8*)(&lnorm[l15][kk * 32 + quad * 8]);
    }
}

// ---------------- Kernel 2: triangular MFMA gram, barrier-free K-loop, XCD-swizzled ----------
// Exact R10 body (proven 43.4 us) + XCD-locality swizzle (2080 = 8*260; blockIdx%8 -> XCD via
// round-robin dispatch heuristic; each XCD walks a contiguous triangular-index range so
// consecutive blocks share ib -> A-tile hot in that XCD's private L2/L1, B streams).
// No LDS staging, no K-loop barriers. Reductions on g (post-norm ||f||^2==1, d2=2-2g monotone
// dec). Col partials -> slot ib rows j; off-diag row partials (16-lane shuffle) -> slot jb
// rows i. Plain stores, no atomics, no fences.
__global__ __launch_bounds__(256, 3) void gram_kernel(const ushort* __restrict__ fn16t,
                                                      const int* __restrict__ lab,
                                                      float* __restrict__ gp_part,
                                                      float* __restrict__ gn_part) {
    __shared__ float cGp[BT][2], cGn[BT][2];   // j-col partials, per wi half
    __shared__ float rGp[BT][2], rGn[BT][2];   // i-row partials, per wj half

    // XCD swizzle then triangular decode (row-major over jb >= ib)
    const int bidx = blockIdx.x;
    const int idx  = (bidx & 7) * 260 + (bidx >> 3);
    const float c = 2.0f * NJB + 1.0f;
    int ib = (int)((c - sqrtf(c * c - 8.0f * (float)idx)) * 0.5f);
    while (ib > 0 && idx < ib * NJB - ib * (ib - 1) / 2) ib--;
    while (idx >= (ib + 1) * NJB - (ib + 1) * ib / 2) ib++;
    const int jb = ib + (idx - (ib * NJB - ib * (ib - 1) / 2));
    const bool offdiag = (jb > ib);
    const int i0 = ib * BT, j0 = jb * BT;

    const int t    = threadIdx.x;
    const int w    = t >> 6;
    const int lane = t & 63;
    const int wi   = w >> 1, wj = w & 1;        // 2x2 waves, each 64x64
    const int quad = lane >> 4;
    const int l15  = lane & 15;

    // fragment base pointers into the tiled layout (group stride = 4096 ushorts)
    const ushort* pA[4];
    const ushort* pB[4];
    #pragma unroll
    for (int m = 0; m < 4; m++)
        pA[m] = fn16t + ((size_t)(ib * 8 + wi * 4 + m)) * 4096 + lane * 8;
    #pragma unroll
    for (int n = 0; n < 4; n++)
        pB[n] = fn16t + ((size_t)(jb * 8 + wj * 4 + n)) * 4096 + lane * 8;

    floatx4 acc[4][4];
    #pragma unroll
    for (int m = 0; m < 4; m++)
        #pragma unroll
        for (int n = 0; n < 4; n++)
            acc[m][n] = (floatx4){0.f, 0.f, 0.f, 0.f};

    // K-loop: 8 steps of K=32, contiguous 1KB fragment loads, no barriers
    #pragma unroll
    for (int kk = 0; kk < 8; kk++) {
        short8 af[4], bf_[4];
        #pragma unroll
        for (int m = 0; m < 4; m++) af[m]  = *(const short8*)(pA[m] + kk * 512);
        #pragma unroll
        for (int n = 0; n < 4; n++) bf_[n] = *(const short8*)(pB[n] + kk * 512);
        #pragma unroll
        for (int m = 0; m < 4; m++)
            #pragma unroll
            for (int n = 0; n < 4; n++)
                acc[m][n] = __builtin_amdgcn_mfma_f32_16x16x32_bf16(af[m], bf_[n], acc[m][n], 0, 0, 0);
    }

    // ---- epilogue on g. C/D layout: col = l15 (tile col wj*64+n*16+l15), row = quad*4 + reg.
    int labj[4];
    #pragma unroll
    for (int n = 0; n < 4; n++) labj[n] = lab[j0 + wj * 64 + n * 16 + l15];
    float gpc[4], gnc[4];
    #pragma unroll
    for (int n = 0; n < 4; n++) { gpc[n] = INFINITY; gnc[n] = -INFINITY; }

    #pragma unroll
    for (int m = 0; m < 4; m++) {
        const int4 li4 = *(const int4*)(lab + i0 + wi * 64 + m * 16 + quad * 4);
        const int labi[4] = {li4.x, li4.y, li4.z, li4.w};
        #pragma unroll
        for (int r = 0; r < 4; r++) {
            float pr = INFINITY, nr = -INFINITY;
            #pragma unroll
            for (int n = 0; n < 4; n++) {
                const float g = acc[m][n][r];
                const bool same = (labi[r] == labj[n]);
                const float selp = same ? g : INFINITY;
                const float seln = same ? -INFINITY : g;
                pr = fminf(pr, selp);           nr = fmaxf(nr, seln);
                gpc[n] = fminf(gpc[n], selp);   gnc[n] = fmaxf(gnc[n], seln);
            }
            if (offdiag) {                      // row-side: 16-lane shuffle reduce (DS idle)
                #pragma unroll
                for (int o = 1; o < 16; o <<= 1) {
                    pr = fminf(pr, __shfl_xor(pr, o));
                    nr = fmaxf(nr, __shfl_xor(nr, o));
                }
                if (l15 == 0) {
                    const int irow = wi * 64 + m * 16 + quad * 4 + r;
                    rGp[irow][wj] = pr; rGn[irow][wj] = nr;
                }
            }
        }
    }
    // column-side: reduce across 4 quads (covers all 64 rows of the wi half)
    #pragma unroll
    for (int n = 0; n < 4; n++) {
        float p = gpc[n], q2 = gnc[n];
        p  = fminf(p,  __shfl_xor(p, 16));  p  = fminf(p,  __shfl_xor(p, 32));
        q2 = fmaxf(q2, __shfl_xor(q2, 16)); q2 = fmaxf(q2, __shfl_xor(q2, 32));
        if (quad == 0) {
            const int col = wj * 64 + n * 16 + l15;
            cGp[col][wi] = p; cGn[col][wi] = q2;
        }
    }
    __syncthreads();
    if (t < BT) {                               // column-side store
        gp_part[(size_t)ib * N + j0 + t] = fminf(cGp[t][0], cGp[t][1]);
        gn_part[(size_t)ib * N + j0 + t] = fmaxf(cGn[t][0], cGn[t][1]);
    } else if (offdiag) {                       // row-side store
        const int i = t - BT;
        gp_part[(size_t)jb * N + i0 + i] = fminf(rGp[i][0], rGp[i][1]);
        gn_part[(size_t)jb * N + i0 + i] = fmaxf(rGn[i][0], rGn[i][1]);
    }
}

// ---------------- Kernel 3: fold slots, sqrt, relu, mean — 256 blocks, coalesced ------------
__global__ __launch_bounds__(256) void reduce_kernel(const float* __restrict__ gp_part,
                                                     const float* __restrict__ gn_part,
                                                     float* __restrict__ out) {
    __shared__ float redp[32][5], redn[32][5];
    const int t  = threadIdx.x;
    const int r  = blockIdx.x * 32 + (t & 31);   // 256 blocks x 32 rows
    const int sg = t >> 5;                        // slot group 0..7
    float gp = INFINITY, gn = -INFINITY;
    #pragma unroll
    for (int q = 0; q < 8; q++) {
        const int s = sg * 8 + q;
        gp = fminf(gp, gp_part[(size_t)s * N + r]);
        gn = fmaxf(gn, gn_part[(size_t)s * N + r]);
    }
    gp = fminf(gp, __shfl_xor(gp, 32));
    gn = fmaxf(gn, __shfl_xor(gn, 32));
    const int w = t >> 6;
    if ((t & 63) < 32) { redp[t & 31][w] = gp; redn[t & 31][w] = gn; }
    __syncthreads();
    if (t < 32) {
        const float p  = fminf(fminf(redp[t][0], redp[t][1]), fminf(redp[t][2], redp[t][3]));
        const float nn = fmaxf(fmaxf(redn[t][0], redn[t][1]), fmaxf(redn[t][2], redn[t][3]));
        const float dp = sqrtf(fmaxf(2.0f - 2.0f * p,  EPS));  // hardest_pos distance
        const float dn = sqrtf(fmaxf(2.0f - 2.0f * nn, EPS));  // hardest_neg distance
        const float l  = dp - dn + MARGIN;
        float sum = (l > 0.0f) ? l : 0.0f;
        #pragma unroll
        for (int off = 16; off; off >>= 1) sum += __shfl_down(sum, off);
        if (t == 0) atomicAdd(out, sum * (1.0f / (float)N));
    }
}

extern "C" void kernel_launch(void* const* d_in, const int* in_sizes, int n_in,
                              void* d_out, int out_size, void* d_ws, size_t ws_size,
                              hipStream_t stream) {
    const float* x   = (const float*)d_in[0];
    const int*   lab = (const int*)d_in[1];
    float* out = (float*)d_out;

    char* ws = (char*)d_ws;
    ushort* fn16t   = (ushort*)ws;                                  // N*D bf16 = 4 MB (tiled)
    float*  gp_part = (float*)(ws + (size_t)N * D * 2);             // NJB*N floats = 2 MB
    float*  gn_part = gp_part + (size_t)NJB * N;                    // NJB*N floats = 2 MB

    normalize_kernel<<<N / 16, 256, 0, stream>>>(x, fn16t, out);
    gram_kernel<<<TOTAL_TRI, 256, 0, stream>>>(fn16t, lab, gp_part, gn_part);
    reduce_kernel<<<N / 32, 256, 0, stream>>>(gp_part, gn_part, out);
}

// Round 13
// 97.313 us; speedup vs baseline: 1.0953x; 1.0913x over previous
//
#include <hip/hip_runtime.h>
#include <hip/hip_bf16.h>
#include <math.h>

#define N 8192
#define D 256
#define MARGIN 0.3f
#define EPS 1e-12f

#define BT 128                             // block tile (i and j)
#define NJB (N / BT)                       // 64 tile-blocks per dim
#define TOTAL_TRI (NJB * (NJB + 1) / 2)    // 2080 upper-triangle tiles = 8 * 260

typedef __attribute__((ext_vector_type(8))) short short8;   // 8 bf16 in 4 VGPRs
typedef __attribute__((ext_vector_type(4))) float floatx4;  // MFMA C/D

static __device__ inline ushort f2bf(float f) {
    __hip_bfloat16 h = __float2bfloat16(f);
    return *reinterpret_cast<ushort*>(&h);
}

// fn16t layout (MFMA-fragment-tiled): element (row r, k) lives at
//   chunk c = (r>>4)*8 + (k>>5), offset (((k>>3)&3)*16 + (r&15))*8 + (k&7)
// so a wave (lane = quad*16+l15) loads fragment (rows g*16..+15, k-step kk) as ONE contiguous
// 1KB transaction: *(short8*)(fn16t + c*512 + lane*8).

// ---------------- Kernel 1: L2 normalize -> bf16 in tiled layout (16 rows/block) -------------
__global__ __launch_bounds__(256) void normalize_kernel(const float* __restrict__ x,
                                                        ushort* __restrict__ fn16t,
                                                        float* __restrict__ out) {
    __shared__ ushort lnorm[16][256];     // 8 KB
    const int g    = blockIdx.x;          // group of 16 rows
    const int t    = threadIdx.x;
    const int w    = t >> 6;
    const int lane = t & 63;
    if (g == 0 && t == 0) out[0] = 0.0f;

    #pragma unroll
    for (int rr = 0; rr < 4; rr++) {
        const int rl  = w * 4 + rr;       // local row 0..15
        const int row = g * 16 + rl;
        float4 v = ((const float4*)(x + (size_t)row * D))[lane];
        float s = v.x * v.x + v.y * v.y + v.z * v.z + v.w * v.w;
        #pragma unroll
        for (int off = 32; off; off >>= 1) s += __shfl_down(s, off);
        s = __shfl(s, 0);
        const float inv = 1.0f / fmaxf(sqrtf(s), 1e-12f);
        ushort4 b;
        b.x = f2bf(v.x * inv); b.y = f2bf(v.y * inv);
        b.z = f2bf(v.z * inv); b.w = f2bf(v.w * inv);
        *(ushort4*)(&lnorm[rl][lane * 4]) = b;
    }
    __syncthreads();
    // write tiled: thread t covers chunk kk = t>>5, two lane-slots p = (t&31)*2 + {0,1}
    const int kk = t >> 5;
    const int pp = (t & 31) * 2;
    ushort* base = fn16t + ((size_t)g * 8 + kk) * 512;
    #pragma unroll
    for (int e = 0; e < 2; e++) {
        const int p    = pp + e;
        const int quad = p >> 4;
        const int l15  = p & 15;
        *(short8*)(base + p * 8) = *(const short8*)(&lnorm[l15][kk * 32 + quad * 8]);
    }
}

// ---------------- Kernel 2: triangular MFMA gram, barrier-free K-loop + rT epilogue ----------
// Exact R12 K-loop (proven 43.4 us: tiled-layout contiguous 1KB fragment loads, no barriers,
// XCD swizzle). Row-side reduction now via LDS transpose (R8-proven): per-(m,r) in-register
// n-fold, write pr/nr to rT[plane][irow][l15] (stride-17 rows), folded by waves 2-3 while
// waves 0-1 store the column side. Replaces 128 ds_swizzle + 128 serial min/max per wave with
// 32 ds_write_b32. Reductions on g (post-norm ||f||^2==1, d2=2-2g monotone dec: hardest_pos =
// min g over positives, hardest_neg = max g over negatives). Plain stores, no atomics/fences.
__global__ __launch_bounds__(256, 3) void gram_kernel(const ushort* __restrict__ fn16t,
                                                      const int* __restrict__ lab,
                                                      float* __restrict__ gp_part,
                                                      float* __restrict__ gn_part) {
    __shared__ float rT[4][BT][17];            // 34816 B; plane = wj*2 + {0:p,1:n}
    __shared__ float cGp[BT][2], cGn[BT][2];   // j-col partials, per wi half

    // XCD swizzle then triangular decode (row-major over jb >= ib)
    const int bidx = blockIdx.x;
    const int idx  = (bidx & 7) * 260 + (bidx >> 3);
    const float c = 2.0f * NJB + 1.0f;
    int ib = (int)((c - sqrtf(c * c - 8.0f * (float)idx)) * 0.5f);
    while (ib > 0 && idx < ib * NJB - ib * (ib - 1) / 2) ib--;
    while (idx >= (ib + 1) * NJB - (ib + 1) * ib / 2) ib++;
    const int jb = ib + (idx - (ib * NJB - ib * (ib - 1) / 2));
    const bool offdiag = (jb > ib);
    const int i0 = ib * BT, j0 = jb * BT;

    const int t    = threadIdx.x;
    const int w    = t >> 6;
    const int lane = t & 63;
    const int wi   = w >> 1, wj = w & 1;        // 2x2 waves, each 64x64
    const int quad = lane >> 4;
    const int l15  = lane & 15;

    // fragment base pointers into the tiled layout (group stride = 4096 ushorts)
    const ushort* pA[4];
    const ushort* pB[4];
    #pragma unroll
    for (int m = 0; m < 4; m++)
        pA[m] = fn16t + ((size_t)(ib * 8 + wi * 4 + m)) * 4096 + lane * 8;
    #pragma unroll
    for (int n = 0; n < 4; n++)
        pB[n] = fn16t + ((size_t)(jb * 8 + wj * 4 + n)) * 4096 + lane * 8;

    floatx4 acc[4][4];
    #pragma unroll
    for (int m = 0; m < 4; m++)
        #pragma unroll
        for (int n = 0; n < 4; n++)
            acc[m][n] = (floatx4){0.f, 0.f, 0.f, 0.f};

    // K-loop: 8 steps of K=32, contiguous 1KB fragment loads, no barriers
    #pragma unroll
    for (int kk = 0; kk < 8; kk++) {
        short8 af[4], bf_[4];
        #pragma unroll
        for (int m = 0; m < 4; m++) af[m]  = *(const short8*)(pA[m] + kk * 512);
        #pragma unroll
        for (int n = 0; n < 4; n++) bf_[n] = *(const short8*)(pB[n] + kk * 512);
        #pragma unroll
        for (int m = 0; m < 4; m++)
            #pragma unroll
            for (int n = 0; n < 4; n++)
                acc[m][n] = __builtin_amdgcn_mfma_f32_16x16x32_bf16(af[m], bf_[n], acc[m][n], 0, 0, 0);
    }

    // ---- epilogue on g. C/D layout: col = l15 (tile col wj*64+n*16+l15), row = quad*4 + reg.
    int labj[4];
    #pragma unroll
    for (int n = 0; n < 4; n++) labj[n] = lab[j0 + wj * 64 + n * 16 + l15];
    float gpc[4], gnc[4];
    #pragma unroll
    for (int n = 0; n < 4; n++) { gpc[n] = INFINITY; gnc[n] = -INFINITY; }

    #pragma unroll
    for (int m = 0; m < 4; m++) {
        const int4 li4 = *(const int4*)(lab + i0 + wi * 64 + m * 16 + quad * 4);
        const int labi[4] = {li4.x, li4.y, li4.z, li4.w};
        #pragma unroll
        for (int r = 0; r < 4; r++) {
            float pr = INFINITY, nr = -INFINITY;
            #pragma unroll
            for (int n = 0; n < 4; n++) {
                const float g = acc[m][n][r];
                const bool same = (labi[r] == labj[n]);
                const float selp = same ? g : INFINITY;
                const float seln = same ? -INFINITY : g;
                pr = fminf(pr, selp);           nr = fmaxf(nr, seln);
                gpc[n] = fminf(gpc[n], selp);   gnc[n] = fmaxf(gnc[n], seln);
            }
            if (offdiag) {                      // row-side: LDS transpose, no shuffle chain
                const int irow = wi * 64 + m * 16 + quad * 4 + r;
                rT[(wj << 1) + 0][irow][l15] = pr;
                rT[(wj << 1) + 1][irow][l15] = nr;
            }
        }
    }
    // column-side: reduce across 4 quads (covers all 64 rows of the wi half)
    #pragma unroll
    for (int n = 0; n < 4; n++) {
        float p = gpc[n], q2 = gnc[n];
        p  = fminf(p,  __shfl_xor(p, 16));  p  = fminf(p,  __shfl_xor(p, 32));
        q2 = fmaxf(q2, __shfl_xor(q2, 16)); q2 = fmaxf(q2, __shfl_xor(q2, 32));
        if (quad == 0) {
            const int col = wj * 64 + n * 16 + l15;
            cGp[col][wi] = p; cGn[col][wi] = q2;
        }
    }
    __syncthreads();
    if (t < BT) {                               // waves 0-1: column-side store
        gp_part[(size_t)ib * N + j0 + t] = fminf(cGp[t][0], cGp[t][1]);
        gn_part[(size_t)ib * N + j0 + t] = fmaxf(cGn[t][0], cGn[t][1]);
    } else if (offdiag) {                       // waves 2-3: fold rT rows, row-side store
        const int i = t - BT;
        float p = INFINITY, nn = -INFINITY;
        #pragma unroll
        for (int k = 0; k < 16; k++) {
            p  = fminf(p,  fminf(rT[0][i][k], rT[2][i][k]));
            nn = fmaxf(nn, fmaxf(rT[1][i][k], rT[3][i][k]));
        }
        gp_part[(size_t)jb * N + i0 + i] = p;
        gn_part[(size_t)jb * N + i0 + i] = nn;
    }
}

// ---------------- Kernel 3: fold slots, sqrt, relu, mean — 256 blocks, coalesced ------------
__global__ __launch_bounds__(256) void reduce_kernel(const float* __restrict__ gp_part,
                                                     const float* __restrict__ gn_part,
                                                     float* __restrict__ out) {
    __shared__ float redp[32][5], redn[32][5];
    const int t  = threadIdx.x;
    const int r  = blockIdx.x * 32 + (t & 31);   // 256 blocks x 32 rows
    const int sg = t >> 5;                        // slot group 0..7
    float gp = INFINITY, gn = -INFINITY;
    #pragma unroll
    for (int q = 0; q < 8; q++) {
        const int s = sg * 8 + q;
        gp = fminf(gp, gp_part[(size_t)s * N + r]);
        gn = fmaxf(gn, gn_part[(size_t)s * N + r]);
    }
    gp = fminf(gp, __shfl_xor(gp, 32));
    gn = fmaxf(gn, __shfl_xor(gn, 32));
    const int w = t >> 6;
    if ((t & 63) < 32) { redp[t & 31][w] = gp; redn[t & 31][w] = gn; }
    __syncthreads();
    if (t < 32) {
        const float p  = fminf(fminf(redp[t][0], redp[t][1]), fminf(redp[t][2], redp[t][3]));
        const float nn = fmaxf(fmaxf(redn[t][0], redn[t][1]), fmaxf(redn[t][2], redn[t][3]));
        const float dp = sqrtf(fmaxf(2.0f - 2.0f * p,  EPS));  // hardest_pos distance
        const float dn = sqrtf(fmaxf(2.0f - 2.0f * nn, EPS));  // hardest_neg distance
        const float l  = dp - dn + MARGIN;
        float sum = (l > 0.0f) ? l : 0.0f;
        #pragma unroll
        for (int off = 16; off; off >>= 1) sum += __shfl_down(sum, off);
        if (t == 0) atomicAdd(out, sum * (1.0f / (float)N));
    }
}

extern "C" void kernel_launch(void* const* d_in, const int* in_sizes, int n_in,
                              void* d_out, int out_size, void* d_ws, size_t ws_size,
                              hipStream_t stream) {
    const float* x   = (const float*)d_in[0];
    const int*   lab = (const int*)d_in[1];
    float* out = (float*)d_out;

    char* ws = (char*)d_ws;
    ushort* fn16t   = (ushort*)ws;                                  // N*D bf16 = 4 MB (tiled)
    float*  gp_part = (float*)(ws + (size_t)N * D * 2);             // NJB*N floats = 2 MB
    float*  gn_part = gp_part + (size_t)NJB * N;                    // NJB*N floats = 2 MB

    normalize_kernel<<<N / 16, 256, 0, stream>>>(x, fn16t, out);
    gram_kernel<<<TOTAL_TRI, 256, 0, stream>>>(fn16t, lab, gp_part, gn_part);
    reduce_kernel<<<N / 32, 256, 0, stream>>>(gp_part, gn_part, out);
}